// Round 2
// baseline (53.429 us; speedup 1.0000x reference)
//
#include <hip/hip_runtime.h>

typedef float f4 __attribute__((ext_vector_type(4)));
typedef float f4u __attribute__((ext_vector_type(4), aligned(4)));

struct M3 { float m[3][3]; };

#define ELEM(q, n) ((q)[(n) >> 2][(n) & 3])

__device__ __forceinline__ M3 matmul(const M3& A, const M3& B) {  // A @ B
  M3 C;
#pragma unroll
  for (int i = 0; i < 3; ++i)
#pragma unroll
    for (int j = 0; j < 3; ++j)
      C.m[i][j] = A.m[i][0]*B.m[0][j] + A.m[i][1]*B.m[1][j] + A.m[i][2]*B.m[2][j];
  return C;
}

__device__ __forceinline__ M3 shfl_mat(const M3& A, int src) {
  M3 C;
#pragma unroll
  for (int i = 0; i < 3; ++i)
#pragma unroll
    for (int j = 0; j < 3; ++j)
      C.m[i][j] = __shfl(A.m[i][j], src, 64);
  return C;
}

// fwd lane: matrix kf of the group, as-is. back lane: matrix kb of the group, transposed.
__device__ __forceinline__ M3 build_D(const f4 (&q)[9], int kf, int kb, bool tb) {
  M3 D;
#pragma unroll
  for (int i = 0; i < 3; ++i)
#pragma unroll
    for (int j = 0; j < 3; ++j) {
      float a = ELEM(q, 9*kf + 3*i + j);
      float c = ELEM(q, 9*kb + 3*j + i);
      D.m[i][j] = tb ? c : a;
    }
  return D;
}

// ---------------- Kernel A: all dirs rows via segmented matrix-prefix scan ----
// 16 lanes per batch element: lanes 0-7 = backward chain segments (rows 8s..8s+7),
// lanes 8-15 = forward chain segments (rows 65+8s..72+8s, clipped at 127).
__global__ __launch_bounds__(64) void dirs_kernel(
    const float* __restrict__ dir, const float* __restrict__ R,
    float* __restrict__ out, int B) {
  const int tid = threadIdx.x;
  const int g = tid >> 4;
  const int l = tid & 15;
  const int s = l & 7;
  const bool tb = (l < 8);              // back-chain lane (transposed matrices)
  const bool skip = (!tb) && (s == 7);  // fwd segment 7 has only 7 frames
  const int b = blockIdx.x * 4 + g;
  if (b >= B) return;

  const float* Rb = R + (size_t)b * 1152;
  const int lo = tb ? (56 - 8*s) : (64 + 8*s);  // lowest frame index of segment
  // first group must supply D0..D3: back = frames lo+4..lo+7, fwd = lo..lo+3
  const int gA = tb ? lo + 4 : lo;
  const int gB = tb ? lo : lo + 4;

  f4 qa[9], qb[9];
  {
    const f4* pA = (const f4*)(Rb + gA * 9);
    const f4* pB = (const f4*)(Rb + gB * 9);
#pragma unroll
    for (int i = 0; i < 9; ++i) { qa[i] = pA[i]; qb[i] = pB[i]; }
  }

  // M[j] = D_j @ D_{j-1} @ ... @ D_0  (partial products; M[7] = segment matrix S)
  M3 M[8];
  M[0] = build_D(qa, 0, 3, tb);
#pragma unroll
  for (int j = 1; j < 4; ++j)
    M[j] = matmul(build_D(qa, j, 3 - j, tb), M[j - 1]);
#pragma unroll
  for (int j = 0; j < 3; ++j)
    M[4 + j] = matmul(build_D(qb, j, 3 - j, tb), M[3 + j]);
  {
    M3 D7 = build_D(qb, 3, 0, tb);
    M3 T = matmul(D7, M[6]);
#pragma unroll
    for (int i = 0; i < 3; ++i)
#pragma unroll
      for (int j = 0; j < 3; ++j)
        M[7].m[i][j] = skip ? M[6].m[i][j] : T.m[i][j];
  }

  // Hillis-Steele inclusive scan over the 8-lane subgroup:
  // I_s = S_s @ S_{s-1} @ ... @ S_0
  M3 I = M[7];
#pragma unroll
  for (int d = 1; d < 8; d <<= 1) {
    M3 Sh = shfl_mat(I, tid - d);
    M3 T = matmul(I, Sh);
#pragma unroll
    for (int i = 0; i < 3; ++i)
#pragma unroll
      for (int j = 0; j < 3; ++j)
        I.m[i][j] = (s >= d) ? T.m[i][j] : I.m[i][j];
  }

  const float d0 = dir[3*b+0], d1 = dir[3*b+1], d2 = dir[3*b+2];
  // w = I @ dir = last row of this segment; v_in = previous lane's w (or dir)
  float w0 = I.m[0][0]*d0 + I.m[0][1]*d1 + I.m[0][2]*d2;
  float w1 = I.m[1][0]*d0 + I.m[1][1]*d1 + I.m[1][2]*d2;
  float w2 = I.m[2][0]*d0 + I.m[2][1]*d1 + I.m[2][2]*d2;
  float p0 = __shfl(w0, tid - 1, 64);
  float p1 = __shfl(w1, tid - 1, 64);
  float p2 = __shfl(w2, tid - 1, 64);
  const float v0 = (s == 0) ? d0 : p0;
  const float v1 = (s == 0) ? d1 : p1;
  const float v2 = (s == 0) ? d2 : p2;

  // rows of this segment: row_j = M[j] @ v_in
  float row[24];
#pragma unroll
  for (int j = 0; j < 8; ++j) {
#pragma unroll
    for (int i = 0; i < 3; ++i)
      row[3*j + i] = M[j].m[i][0]*v0 + M[j].m[i][1]*v1 + M[j].m[i][2]*v2;
  }

  const int rowBase = tb ? 8*s : 65 + 8*s;
  float* ob = out + (size_t)b * 384 + (size_t)rowBase * 3;
#pragma unroll
  for (int k = 0; k < 5; ++k) {
    f4u v = { row[4*k+0], row[4*k+1], row[4*k+2], row[4*k+3] };
    *(f4u*)(ob + 4*k) = v;
  }
  ob[20] = row[20];
  if (!skip) { ob[21] = row[21]; ob[22] = row[22]; ob[23] = row[23]; }
}

// ---------------- Kernel B: tiny 3-unit LSTM over back rows + dir -------------
__device__ __forceinline__ float sigm(float z) {
  return __builtin_amdgcn_rcpf(1.0f + __expf(-z));
}
__device__ __forceinline__ float tanh_(float z) {
  float e = __expf(2.0f * z);
  return 1.0f - 2.0f * __builtin_amdgcn_rcpf(e + 1.0f);
}

__device__ __forceinline__ void lstm_step(
    float x0, float x1, float x2,
    float& h0, float& h1, float& h2,
    float& c0, float& c1, float& c2,
    const float (&wi)[12][3], const float (&wh)[12][3], const float (&bs)[12]) {
  float gg[12];
#pragma unroll
  for (int k = 0; k < 12; ++k) {
    gg[k] = bs[k] + wi[k][0]*x0 + wi[k][1]*x1 + wi[k][2]*x2
                  + wh[k][0]*h0 + wh[k][1]*h1 + wh[k][2]*h2;
  }
  float i0 = sigm(gg[0]),  i1 = sigm(gg[1]),  i2 = sigm(gg[2]);
  float f0 = sigm(gg[3]),  f1 = sigm(gg[4]),  f2 = sigm(gg[5]);
  float t0 = tanh_(gg[6]), t1 = tanh_(gg[7]), t2 = tanh_(gg[8]);
  float o0 = sigm(gg[9]),  o1 = sigm(gg[10]), o2 = sigm(gg[11]);
  c0 = f0*c0 + i0*t0; c1 = f1*c1 + i1*t1; c2 = f2*c2 + i2*t2;
  h0 = o0*tanh_(c0); h1 = o1*tanh_(c1); h2 = o2*tanh_(c2);
}

__global__ __launch_bounds__(64) void lstm_kernel(
    const float* __restrict__ dir,
    const float* __restrict__ Wih, const float* __restrict__ Whh,
    const float* __restrict__ bih, const float* __restrict__ bhh,
    float* __restrict__ out, int B) {
  const int b = blockIdx.x * 64 + threadIdx.x;
  if (b >= B) return;

  float wi[12][3], wh[12][3], bs[12];
#pragma unroll
  for (int k = 0; k < 12; ++k) {
#pragma unroll
    for (int j = 0; j < 3; ++j) { wi[k][j] = Wih[k*3+j]; wh[k][j] = Whh[k*3+j]; }
    bs[k] = bih[k] + bhh[k];
  }

  float* ob = out + (size_t)b * 384;
  float h0 = 0.f, h1 = 0.f, h2 = 0.f, c0 = 0.f, c1 = 0.f, c2 = 0.f;

  f4 buf0[12], buf1[12];
  {
    const f4* p = (const f4*)ob;
#pragma unroll
    for (int i = 0; i < 12; ++i) buf0[i] = p[i];
  }
#pragma unroll
  for (int c = 0; c < 4; ++c) {
    if (c < 3) {
      const f4* p = (const f4*)(ob + (c + 1) * 48);
      if ((c & 1) == 0) {
#pragma unroll
        for (int i = 0; i < 12; ++i) buf1[i] = p[i];
      } else {
#pragma unroll
        for (int i = 0; i < 12; ++i) buf0[i] = p[i];
      }
    }
#pragma unroll
    for (int t = 0; t < 16; ++t) {
      float x0, x1, x2;
      if ((c & 1) == 0) {
        x0 = ELEM(buf0, 3*t+0); x1 = ELEM(buf0, 3*t+1); x2 = ELEM(buf0, 3*t+2);
      } else {
        x0 = ELEM(buf1, 3*t+0); x1 = ELEM(buf1, 3*t+1); x2 = ELEM(buf1, 3*t+2);
      }
      lstm_step(x0, x1, x2, h0, h1, h2, c0, c1, c2, wi, wh, bs);
    }
  }
  // final step t=64 with x = dir; h replaces row 64
  const float d0 = dir[3*b+0], d1 = dir[3*b+1], d2 = dir[3*b+2];
  lstm_step(d0, d1, d2, h0, h1, h2, c0, c1, c2, wi, wh, bs);
  ob[192] = h0; ob[193] = h1; ob[194] = h2;
}

extern "C" void kernel_launch(void* const* d_in, const int* in_sizes, int n_in,
                              void* d_out, int out_size, void* d_ws, size_t ws_size,
                              hipStream_t stream) {
  const float* dir = (const float*)d_in[0];
  const float* R   = (const float*)d_in[1];
  const float* Wih = (const float*)d_in[2];
  const float* Whh = (const float*)d_in[3];
  const float* bih = (const float*)d_in[4];
  const float* bhh = (const float*)d_in[5];
  float* out = (float*)d_out;

  const int B = in_sizes[0] / 3;  // 16384
  const int gridA = (B + 3) / 4;    // 16 lanes per element, 4 elements per wave
  hipLaunchKernelGGL(dirs_kernel, dim3(gridA), dim3(64), 0, stream, dir, R, out, B);
  const int gridB = (B + 63) / 64;
  hipLaunchKernelGGL(lstm_kernel, dim3(gridB), dim3(64), 0, stream,
                     dir, Wih, Whh, bih, bhh, out, B);
}

// Round 4
// 43.796 us; speedup vs baseline: 1.2199x; 1.2199x over previous
//
#include <hip/hip_runtime.h>

typedef float f4 __attribute__((ext_vector_type(4)));
typedef float f4u __attribute__((ext_vector_type(4), aligned(4)));

struct M3 { float m[3][3]; };

#define ELEM(q, n) ((q)[(n) >> 2][(n) & 3])

__device__ __forceinline__ M3 matmul(const M3& A, const M3& B) {  // A @ B
  M3 C;
#pragma unroll
  for (int i = 0; i < 3; ++i)
#pragma unroll
    for (int j = 0; j < 3; ++j)
      C.m[i][j] = A.m[i][0]*B.m[0][j] + A.m[i][1]*B.m[1][j] + A.m[i][2]*B.m[2][j];
  return C;
}

__device__ __forceinline__ M3 shfl_mat(const M3& A, int src) {
  M3 C;
#pragma unroll
  for (int i = 0; i < 3; ++i)
#pragma unroll
    for (int j = 0; j < 3; ++j)
      C.m[i][j] = __shfl(A.m[i][j], src, 64);
  return C;
}

// fwd lane: matrix kf of the group, as-is. back lane: matrix kb of the group, transposed.
__device__ __forceinline__ M3 build_D(const f4 (&q)[9], int kf, int kb, bool tb) {
  M3 D;
#pragma unroll
  for (int i = 0; i < 3; ++i)
#pragma unroll
    for (int j = 0; j < 3; ++j) {
      float a = ELEM(q, 9*kf + 3*i + j);
      float c = ELEM(q, 9*kb + 3*j + i);
      D.m[i][j] = tb ? c : a;
    }
  return D;
}

// Fused: segmented matrix-prefix scan for all dirs rows + in-wave gate-parallel LSTM.
// 16 lanes per element: lanes 0-7 back segments (rows 8s..8s+7, transposed mats),
// lanes 8-15 fwd segments (rows 65+8s.., clipped at 127). LSTM: lanes 0-11 = one
// gate row each; x_t pulled by shuffle from the back-lane row registers.
__global__ __launch_bounds__(64) void fused_kernel(
    const float* __restrict__ dir, const float* __restrict__ R,
    const float* __restrict__ Wih, const float* __restrict__ Whh,
    const float* __restrict__ bih, const float* __restrict__ bhh,
    float* __restrict__ out, int B) {
  const int tid = threadIdx.x;
  const int l = tid & 15;
  const int s = l & 7;
  const bool tb = (l < 8);              // back-chain lane
  const bool skip = (!tb) && (s == 7);  // fwd segment 7 has only 7 frames
  const int base = tid & ~15;           // first lane of this element's group
  const int b = blockIdx.x * 4 + (tid >> 4);
  if (b >= B) return;

  const float* Rb = R + (size_t)b * 1152;
  const int lo = tb ? (56 - 8*s) : (64 + 8*s);
  const int gA = tb ? lo + 4 : lo;   // group supplying D0..D3
  const int gB = tb ? lo : lo + 4;   // group supplying D4..D7

  f4 qa[9], qb[9];
  {
    const f4* pA = (const f4*)(Rb + gA * 9);
    const f4* pB = (const f4*)(Rb + gB * 9);
#pragma unroll
    for (int i = 0; i < 9; ++i) { qa[i] = pA[i]; qb[i] = pB[i]; }
  }

  // LSTM per-lane constants (gate k = l for l < 12)
  const int k = (l < 12) ? l : 0;
  const float wi0 = Wih[3*k+0], wi1 = Wih[3*k+1], wi2 = Wih[3*k+2];
  const float wh0 = Whh[3*k+0], wh1 = Whh[3*k+1], wh2 = Whh[3*k+2];
  const float bsk = bih[k] + bhh[k];
  const bool is_g = (l >= 6 && l < 9);          // g-gates use tanh
  const float mz  = is_g ? -2.0f : -1.0f;       // exp(mz*z)
  const float asc = is_g ?  2.0f :  1.0f;       // a = asc*r + aof
  const float aof = is_g ? -1.0f :  0.0f;
  const int ug = (l < 3) ? l : 0;               // unit index for c/h lanes

  // ---- segment product S = D7 @ ... @ D0 (one running matrix) ----
  M3 S = build_D(qa, 0, 3, tb);
#pragma unroll
  for (int j = 1; j < 4; ++j) S = matmul(build_D(qa, j, 3 - j, tb), S);
#pragma unroll
  for (int j = 0; j < 4; ++j) S = matmul(build_D(qb, j, 3 - j, tb), S);
  // (skip lane includes frame 127 in S; its scan result is never consumed)

  // ---- Hillis-Steele inclusive scan over the 8-lane subgroup ----
  M3 I = S;
#pragma unroll
  for (int d = 1; d < 8; d <<= 1) {
    M3 Sh = shfl_mat(I, tid - d);
    M3 T = matmul(I, Sh);
#pragma unroll
    for (int i = 0; i < 3; ++i)
#pragma unroll
      for (int j = 0; j < 3; ++j)
        I.m[i][j] = (s >= d) ? T.m[i][j] : I.m[i][j];
  }

  const float d0 = dir[3*b+0], d1 = dir[3*b+1], d2 = dir[3*b+2];
  float w0 = I.m[0][0]*d0 + I.m[0][1]*d1 + I.m[0][2]*d2;
  float w1 = I.m[1][0]*d0 + I.m[1][1]*d1 + I.m[1][2]*d2;
  float w2 = I.m[2][0]*d0 + I.m[2][1]*d1 + I.m[2][2]*d2;
  float p0 = __shfl(w0, tid - 1, 64);
  float p1 = __shfl(w1, tid - 1, 64);
  float p2 = __shfl(w2, tid - 1, 64);
  float v0 = (s == 0) ? d0 : p0;
  float v1 = (s == 0) ? d1 : p1;
  float v2 = (s == 0) ? d2 : p2;

  // ---- rows by chaining v <- D_j @ v (qa/qb still live; no M[8] array) ----
  float row[24];
#pragma unroll
  for (int j = 0; j < 8; ++j) {
    M3 D = (j < 4) ? build_D(qa, j, 3 - j, tb) : build_D(qb, j - 4, 7 - j, tb);
    float n0 = D.m[0][0]*v0 + D.m[0][1]*v1 + D.m[0][2]*v2;
    float n1 = D.m[1][0]*v0 + D.m[1][1]*v1 + D.m[1][2]*v2;
    float n2 = D.m[2][0]*v0 + D.m[2][1]*v1 + D.m[2][2]*v2;
    v0 = n0; v1 = n1; v2 = n2;
    row[3*j+0] = n0; row[3*j+1] = n1; row[3*j+2] = n2;
  }

  float* obE = out + (size_t)b * 384;
  {
    const int rowBase = tb ? 8*s : 65 + 8*s;
    float* ob = obE + (size_t)rowBase * 3;
#pragma unroll
    for (int kk = 0; kk < 5; ++kk) {
      f4u vv = { row[4*kk+0], row[4*kk+1], row[4*kk+2], row[4*kk+3] };
      *(f4u*)(ob + 4*kk) = vv;
    }
    ob[20] = row[20];
    if (!skip) { ob[21] = row[21]; ob[22] = row[22]; ob[23] = row[23]; }
  }

  // ---- in-wave LSTM: 12 gate-lanes per element, 65 steps ----
  float h0 = 0.f, h1 = 0.f, h2 = 0.f, cc = 0.f;

#define LSTM_STEP(x0_, x1_, x2_)                                              \
  {                                                                           \
    float z = bsk + wi0*(x0_) + wi1*(x1_) + wi2*(x2_)                         \
                  + wh0*h0 + wh1*h1 + wh2*h2;                                 \
    float u = __expf(z * mz);                                                 \
    float r = __builtin_amdgcn_rcpf(1.0f + u);                                \
    float a = asc * r + aof;                                                  \
    float af = __shfl(a, base + 3 + ug, 64);                                  \
    float ag = __shfl(a, base + 6 + ug, 64);                                  \
    float ao = __shfl(a, base + 9 + ug, 64);                                  \
    float cn = af * cc + a * ag;                                              \
    cc = cn;                                                                  \
    float e2 = __expf(-2.0f * cn);                                            \
    float th = 2.0f * __builtin_amdgcn_rcpf(1.0f + e2) - 1.0f;                \
    float hn = ao * th;                                                       \
    h0 = __shfl(hn, base + 0, 64);                                            \
    h1 = __shfl(hn, base + 1, 64);                                            \
    h2 = __shfl(hn, base + 2, 64);                                            \
  }

#pragma unroll
  for (int c8 = 0; c8 < 8; ++c8) {
#pragma unroll
    for (int j = 0; j < 8; ++j) {
      float x0 = __shfl(row[3*j+0], base + c8, 64);
      float x1 = __shfl(row[3*j+1], base + c8, 64);
      float x2 = __shfl(row[3*j+2], base + c8, 64);
      LSTM_STEP(x0, x1, x2);
    }
  }
  // final step t=64 with x = dir; h replaces row 64
  LSTM_STEP(d0, d1, d2);
#undef LSTM_STEP

  if (l < 3) {
    float hv = (l == 0) ? h0 : ((l == 1) ? h1 : h2);
    obE[192 + l] = hv;
  }
}

extern "C" void kernel_launch(void* const* d_in, const int* in_sizes, int n_in,
                              void* d_out, int out_size, void* d_ws, size_t ws_size,
                              hipStream_t stream) {
  const float* dir = (const float*)d_in[0];
  const float* R   = (const float*)d_in[1];
  const float* Wih = (const float*)d_in[2];
  const float* Whh = (const float*)d_in[3];
  const float* bih = (const float*)d_in[4];
  const float* bhh = (const float*)d_in[5];
  float* out = (float*)d_out;

  const int B = in_sizes[0] / 3;  // 16384
  const int grid = (B + 3) / 4;   // 4 elements per wave, 16 lanes each
  hipLaunchKernelGGL(fused_kernel, dim3(grid), dim3(64), 0, stream,
                     dir, R, Wih, Whh, bih, bhh, out, B);
}